// Round 2
// baseline (516.149 us; speedup 1.0000x reference)
//
#include <hip/hip_runtime.h>
#include <stdint.h>

#define GLOBAL_AS __attribute__((address_space(1)))
#define LDS_AS __attribute__((address_space(3)))

typedef int v4i  __attribute__((ext_vector_type(4)));
typedef int v16i __attribute__((ext_vector_type(16)));

static constexpr int M = 8192;
static constexpr int N = 4096;
static constexpr int K = 4096;
static constexpr float F_EPS = 1e-5f;

// ws byte layout:
//   0: float s_x (=128/gamma)   4: float wscale   8: float outscale
//   256:  float pmax[1024]
//   4352: double psum[512]
//   16384: xq[M*K]  then wq[N*K]

// ---------------- fused reductions: absmax(x) partials + sum|w| partials ----------------
__global__ void reduce_kernel(const float4* __restrict__ x, const float4* __restrict__ w,
                              float* __restrict__ pmax, double* __restrict__ psum) {
    const int b = blockIdx.x;
    const int t = threadIdx.x;
    if (b < 1024) {
        float m = 0.f;
        const int n4 = M * K / 4;
        for (int i = b * 256 + t; i < n4; i += 1024 * 256) {
            float4 v = x[i];
            m = fmaxf(m, fmaxf(fmaxf(fabsf(v.x), fabsf(v.y)), fmaxf(fabsf(v.z), fabsf(v.w))));
        }
#pragma unroll
        for (int off = 32; off > 0; off >>= 1) m = fmaxf(m, __shfl_down(m, off, 64));
        __shared__ float red[4];
        if ((t & 63) == 0) red[t >> 6] = m;
        __syncthreads();
        if (t == 0) pmax[b] = fmaxf(fmaxf(red[0], red[1]), fmaxf(red[2], red[3]));
    } else {
        double s = 0.0;
        const int n4 = N * K / 4;
        for (int i = (b - 1024) * 256 + t; i < n4; i += 512 * 256) {
            float4 v = w[i];
            s += (double)fabsf(v.x);
            s += (double)fabsf(v.y);
            s += (double)fabsf(v.z);
            s += (double)fabsf(v.w);
        }
#pragma unroll
        for (int off = 32; off > 0; off >>= 1) s += __shfl_down(s, off, 64);
        __shared__ double dred[4];
        if ((t & 63) == 0) dred[t >> 6] = s;
        __syncthreads();
        if (t == 0) psum[b - 1024] = dred[0] + dred[1] + dred[2] + dred[3];
    }
}

// ---------------- finalize scalars ----------------
__global__ void finalize_kernel(float* __restrict__ wssc, const float* __restrict__ pmax,
                                const double* __restrict__ psum) {
    const int t = threadIdx.x;
    float m = 0.f;
    for (int i = t; i < 1024; i += 256) m = fmaxf(m, pmax[i]);
#pragma unroll
    for (int off = 32; off > 0; off >>= 1) m = fmaxf(m, __shfl_down(m, off, 64));
    double s = psum[t] + psum[t + 256];  // t<256, psum has 512
#pragma unroll
    for (int off = 32; off > 0; off >>= 1) s += __shfl_down(s, off, 64);
    __shared__ float red[4];
    __shared__ double dred[4];
    if ((t & 63) == 0) { red[t >> 6] = m; dred[t >> 6] = s; }
    __syncthreads();
    if (t == 0) {
        float gamma = fmaxf(fmaxf(fmaxf(red[0], red[1]), fmaxf(red[2], red[3])), F_EPS);
        double sum = dred[0] + dred[1] + dred[2] + dred[3];
        float wscale = (float)fmax(sum * (1.0 / ((double)N * (double)K)), (double)F_EPS);
        wssc[0] = 128.f / gamma;
        wssc[1] = wscale;
        wssc[2] = gamma * wscale / 128.f;
    }
}

// ---------------- fused quantization: x->int8, w->ternary ----------------
__global__ void quant_kernel(const float4* __restrict__ x, const float4* __restrict__ w,
                             int* __restrict__ xq, int* __restrict__ wq,
                             const float* __restrict__ wssc) {
    const int b = blockIdx.x;
    const int t = threadIdx.x;
    if (b < 2048) {
        const float s = wssc[0];
        const int n4 = M * K / 4;
        for (int i = b * 256 + t; i < n4; i += 2048 * 256) {
            float4 v = x[i];
            int q0 = min(127, max(-128, (int)rintf(v.x * s)));
            int q1 = min(127, max(-128, (int)rintf(v.y * s)));
            int q2 = min(127, max(-128, (int)rintf(v.z * s)));
            int q3 = min(127, max(-128, (int)rintf(v.w * s)));
            xq[i] = (q0 & 255) | ((q1 & 255) << 8) | ((q2 & 255) << 16) | (q3 << 24);
        }
    } else {
        const float ws = wssc[1];
        const int n4 = N * K / 4;
        for (int i = (b - 2048) * 256 + t; i < n4; i += 1024 * 256) {
            float4 v = w[i];
            int q0 = min(1, max(-1, (int)rintf(v.x / ws)));
            int q1 = min(1, max(-1, (int)rintf(v.y / ws)));
            int q2 = min(1, max(-1, (int)rintf(v.z / ws)));
            int q3 = min(1, max(-1, (int)rintf(v.w / ws)));
            wq[i] = (q0 & 255) | ((q1 & 255) << 8) | ((q2 & 255) << 16) | (q3 << 24);
        }
    }
}

// ---------------- int8 GEMM, 256x256 block tile, 4 waves (each 128x128), dbuf LDS ----------------
__global__ __launch_bounds__(256, 1) void gemm_kernel(
    const int8_t* __restrict__ xq, const int8_t* __restrict__ wq,
    const float* __restrict__ bias, const float* __restrict__ wssc,
    float* __restrict__ out) {

    __shared__ __align__(16) int8_t As0[256 * 64];
    __shared__ __align__(16) int8_t As1[256 * 64];
    __shared__ __align__(16) int8_t Bs0[256 * 64];
    __shared__ __align__(16) int8_t Bs1[256 * 64];

    const int t = threadIdx.x;
    const int lane = t & 63;
    const int wv = t >> 6;
    const int half = lane >> 5;
    const int lr = lane & 31;
    const int wrow0 = (wv >> 1) * 128;
    const int wcol0 = (wv & 1) * 128;
    const int m0 = blockIdx.x * 256;
    const int n0 = blockIdx.y * 256;

    // ---- staging source pointers (global side stays coalesced: 8 runs of 128B per 64 lanes) ----
    // LDS chunk = 1KB = 16 rows x 4 k-blocks(16B). slot s: k=s>>4, rho=((s&15)-4k)&15
    // => bank-quad(row,k) = (row+4k)&7: halves offset by 4 => conflict-free b128 reads.
    const GLOBAL_AS int8_t* aSrc[4];
    const GLOBAL_AS int8_t* bSrc[4];
    int sLds[4];
#pragma unroll
    for (int j = 0; j < 4; ++j) {
        int idx = j * 256 + t;       // 0..1023 16B-slot index
        int c = idx >> 6;            // chunk (16 rows)
        int s = idx & 63;
        int k = s >> 4;              // kblk 0..3
        int rho = ((s & 15) - 4 * k) & 15;
        int row = c * 16 + rho;
        aSrc[j] = (const GLOBAL_AS int8_t*)(xq + (size_t)(m0 + row) * K + k * 16);
        bSrc[j] = (const GLOBAL_AS int8_t*)(wq + (size_t)(n0 + row) * K + k * 16);
        sLds[j] = idx * 16;
    }

    // ---- fragment LDS offsets (ks in {0,1} covers K=64; k = ks*2 + half) ----
    int aOff[2][4], bOff[2][4];
#pragma unroll
    for (int ks = 0; ks < 2; ++ks) {
        int k = ks * 2 + half;
#pragma unroll
        for (int q = 0; q < 4; ++q) {
            int ra = wrow0 + q * 32 + lr;
            aOff[ks][q] = (ra >> 4) * 1024 + k * 256 + (((ra & 15) + 4 * k) & 15) * 16;
            int rb = wcol0 + q * 32 + lr;
            bOff[ks][q] = (rb >> 4) * 1024 + k * 256 + (((rb & 15) + 4 * k) & 15) * 16;
        }
    }

    v16i acc[4][4];
#pragma unroll
    for (int mt = 0; mt < 4; ++mt)
#pragma unroll
        for (int nt = 0; nt < 4; ++nt)
#pragma unroll
            for (int e = 0; e < 16; ++e) acc[mt][nt][e] = 0;

    auto stage = [&](int kt, int8_t* A, int8_t* B) {
#pragma unroll
        for (int j = 0; j < 4; ++j) {
            __builtin_amdgcn_global_load_lds((const GLOBAL_AS void*)(aSrc[j] + kt),
                                             (LDS_AS void*)(A + sLds[j]), 16, 0, 0);
            __builtin_amdgcn_global_load_lds((const GLOBAL_AS void*)(bSrc[j] + kt),
                                             (LDS_AS void*)(B + sLds[j]), 16, 0, 0);
        }
    };

    auto compute = [&](const int8_t* A, const int8_t* B) {
#pragma unroll
        for (int ks = 0; ks < 2; ++ks) {
            v4i a[4], b[4];
#pragma unroll
            for (int q = 0; q < 4; ++q) a[q] = *(const v4i*)(A + aOff[ks][q]);
#pragma unroll
            for (int q = 0; q < 4; ++q) b[q] = *(const v4i*)(B + bOff[ks][q]);
#pragma unroll
            for (int mt = 0; mt < 4; ++mt)
#pragma unroll
                for (int nt = 0; nt < 4; ++nt)
                    acc[mt][nt] = __builtin_amdgcn_mfma_i32_32x32x32_i8(a[mt], b[nt], acc[mt][nt], 0, 0, 0);
        }
    };

    constexpr int NIT = K / 64;  // 64 tiles
    stage(0, As0, Bs0);
    __syncthreads();
#pragma unroll 1
    for (int it = 0; it < NIT - 2; it += 2) {
        stage((it + 1) * 64, As1, Bs1);   // in flight during compute on buf0
        compute(As0, Bs0);
        __syncthreads();                  // drains aged loads; protects buf reuse
        stage((it + 2) * 64, As0, Bs0);
        compute(As1, Bs1);
        __syncthreads();
    }
    stage((NIT - 1) * 64, As1, Bs1);
    compute(As0, Bs0);
    __syncthreads();
    compute(As1, Bs1);

    // ---- epilogue: C/D layout col=lane&31, row=(reg&3)+8*(reg>>2)+4*(lane>>5) ----
    const float scale = wssc[2];
#pragma unroll
    for (int nt = 0; nt < 4; ++nt) {
        int col = n0 + wcol0 + nt * 32 + lr;
        float bv = bias[col];
#pragma unroll
        for (int mt = 0; mt < 4; ++mt) {
            int rb = m0 + wrow0 + mt * 32 + 4 * half;
#pragma unroll
            for (int reg = 0; reg < 16; ++reg) {
                int row = rb + (reg & 3) + 8 * (reg >> 2);
                out[(size_t)row * N + col] = (float)acc[mt][nt][reg] * scale + bv;
            }
        }
    }
}

extern "C" void kernel_launch(void* const* d_in, const int* in_sizes, int n_in,
                              void* d_out, int out_size, void* d_ws, size_t ws_size,
                              hipStream_t stream) {
    const float* x = (const float*)d_in[0];     // [8192][4096]
    const float* w = (const float*)d_in[1];     // [4096][4096]
    const float* bias = (const float*)d_in[2];  // [4096]
    float* out = (float*)d_out;                 // [8192][4096]

    float* wssc = (float*)d_ws;
    float* pmax = (float*)((char*)d_ws + 256);
    double* psum = (double*)((char*)d_ws + 4352);
    int8_t* xq = (int8_t*)d_ws + 16384;
    int8_t* wq = xq + (size_t)M * K;

    hipLaunchKernelGGL(reduce_kernel, dim3(1536), dim3(256), 0, stream,
                       (const float4*)x, (const float4*)w, pmax, psum);
    hipLaunchKernelGGL(finalize_kernel, dim3(1), dim3(256), 0, stream, wssc, pmax, psum);
    hipLaunchKernelGGL(quant_kernel, dim3(3072), dim3(256), 0, stream,
                       (const float4*)x, (const float4*)w, (int*)xq, (int*)wq, wssc);
    hipLaunchKernelGGL(gemm_kernel, dim3(M / 256, N / 256), dim3(256), 0, stream,
                       xq, wq, bias, wssc, out);
}

// Round 3
// 489.466 us; speedup vs baseline: 1.0545x; 1.0545x over previous
//
#include <hip/hip_runtime.h>
#include <stdint.h>

#define GLOBAL_AS __attribute__((address_space(1)))
#define LDS_AS __attribute__((address_space(3)))

typedef int v4i  __attribute__((ext_vector_type(4)));
typedef int v16i __attribute__((ext_vector_type(16)));

static constexpr int M = 8192;
static constexpr int N = 4096;
static constexpr int K = 4096;
static constexpr float F_EPS = 1e-5f;

// ws layout: 0: wssc[3] (s_x, wscale, outscale) | 256: pmax[2048] f32 | 8448: psum[1024] f64
//            16640: xq[M*K] i8 | +32MiB: wq[N*K] i8

// ---------------- fused reductions ----------------
__global__ void reduce_kernel(const float4* __restrict__ x, const float4* __restrict__ w,
                              float* __restrict__ pmax, double* __restrict__ psum) {
    const int b = blockIdx.x;
    const int t = threadIdx.x;
    if (b < 2048) {
        float m = 0.f;
        const int n4 = M * K / 4;           // 8M float4
        int i = b * 512 + t;
        for (; i + 256 < n4; i += 2048 * 512) {
            float4 v0 = x[i];
            float4 v1 = x[i + 256];
            m = fmaxf(m, fmaxf(fmaxf(fabsf(v0.x), fabsf(v0.y)), fmaxf(fabsf(v0.z), fabsf(v0.w))));
            m = fmaxf(m, fmaxf(fmaxf(fabsf(v1.x), fabsf(v1.y)), fmaxf(fabsf(v1.z), fabsf(v1.w))));
        }
#pragma unroll
        for (int off = 32; off > 0; off >>= 1) m = fmaxf(m, __shfl_down(m, off, 64));
        __shared__ float red[4];
        if ((t & 63) == 0) red[t >> 6] = m;
        __syncthreads();
        if (t == 0) pmax[b] = fmaxf(fmaxf(red[0], red[1]), fmaxf(red[2], red[3]));
    } else {
        double s = 0.0;
        const int n4 = N * K / 4;           // 4M float4
        int i = (b - 2048) * 512 + t;
        for (; i + 256 < n4; i += 1024 * 512) {
            float4 v0 = w[i];
            float4 v1 = w[i + 256];
            s += (double)fabsf(v0.x) + (double)fabsf(v0.y) + (double)fabsf(v0.z) + (double)fabsf(v0.w);
            s += (double)fabsf(v1.x) + (double)fabsf(v1.y) + (double)fabsf(v1.z) + (double)fabsf(v1.w);
        }
#pragma unroll
        for (int off = 32; off > 0; off >>= 1) s += __shfl_down(s, off, 64);
        __shared__ double dred[4];
        if ((t & 63) == 0) dred[t >> 6] = s;
        __syncthreads();
        if (t == 0) psum[b - 2048] = dred[0] + dred[1] + dred[2] + dred[3];
    }
}

// ---------------- finalize scalars ----------------
__global__ void finalize_kernel(float* __restrict__ wssc, const float* __restrict__ pmax,
                                const double* __restrict__ psum) {
    const int t = threadIdx.x;
    float m = 0.f;
#pragma unroll
    for (int j = 0; j < 8; ++j) m = fmaxf(m, pmax[t + j * 256]);
#pragma unroll
    for (int off = 32; off > 0; off >>= 1) m = fmaxf(m, __shfl_down(m, off, 64));
    double s = psum[t] + psum[t + 256] + psum[t + 512] + psum[t + 768];
#pragma unroll
    for (int off = 32; off > 0; off >>= 1) s += __shfl_down(s, off, 64);
    __shared__ float red[4];
    __shared__ double dred[4];
    if ((t & 63) == 0) { red[t >> 6] = m; dred[t >> 6] = s; }
    __syncthreads();
    if (t == 0) {
        float gamma = fmaxf(fmaxf(fmaxf(red[0], red[1]), fmaxf(red[2], red[3])), F_EPS);
        double sum = dred[0] + dred[1] + dred[2] + dred[3];
        float wscale = (float)fmax(sum * (1.0 / ((double)N * (double)K)), (double)F_EPS);
        wssc[0] = 128.f / gamma;
        wssc[1] = wscale;
        wssc[2] = gamma * wscale / 128.f;
    }
}

// ---------------- fused quantization ----------------
__global__ void quant_kernel(const float4* __restrict__ x, const float4* __restrict__ w,
                             int* __restrict__ xq, int* __restrict__ wq,
                             const float* __restrict__ wssc) {
    const int b = blockIdx.x;
    const int t = threadIdx.x;
    if (b < 2048) {
        const float s = wssc[0];
        const int n4 = M * K / 4;
        int i = b * 512 + t;
        for (; i + 256 < n4; i += 2048 * 512) {
            float4 v0 = x[i];
            float4 v1 = x[i + 256];
            int a0 = min(127, max(-128, (int)rintf(v0.x * s)));
            int a1 = min(127, max(-128, (int)rintf(v0.y * s)));
            int a2 = min(127, max(-128, (int)rintf(v0.z * s)));
            int a3 = min(127, max(-128, (int)rintf(v0.w * s)));
            xq[i] = (a0 & 255) | ((a1 & 255) << 8) | ((a2 & 255) << 16) | (a3 << 24);
            int b0 = min(127, max(-128, (int)rintf(v1.x * s)));
            int b1 = min(127, max(-128, (int)rintf(v1.y * s)));
            int b2 = min(127, max(-128, (int)rintf(v1.z * s)));
            int b3 = min(127, max(-128, (int)rintf(v1.w * s)));
            xq[i + 256] = (b0 & 255) | ((b1 & 255) << 8) | ((b2 & 255) << 16) | (b3 << 24);
        }
    } else {
        const float ws = wssc[1];
        const int n4 = N * K / 4;
        int i = (b - 2048) * 512 + t;
        for (; i + 256 < n4; i += 1024 * 512) {
            float4 v0 = w[i];
            float4 v1 = w[i + 256];
            int a0 = min(1, max(-1, (int)rintf(v0.x / ws)));
            int a1 = min(1, max(-1, (int)rintf(v0.y / ws)));
            int a2 = min(1, max(-1, (int)rintf(v0.z / ws)));
            int a3 = min(1, max(-1, (int)rintf(v0.w / ws)));
            wq[i] = (a0 & 255) | ((a1 & 255) << 8) | ((a2 & 255) << 16) | (a3 << 24);
            int b0 = min(1, max(-1, (int)rintf(v1.x / ws)));
            int b1 = min(1, max(-1, (int)rintf(v1.y / ws)));
            int b2 = min(1, max(-1, (int)rintf(v1.z / ws)));
            int b3 = min(1, max(-1, (int)rintf(v1.w / ws)));
            wq[i + 256] = (b0 & 255) | ((b1 & 255) << 8) | ((b2 & 255) << 16) | (b3 << 24);
        }
    }
}

// ---------------- int8 GEMM: 128x256 block, 4 waves (each 64x128), BK=64 dbuf ----------------
// LDS chunked layout: chunk = 16 rows x 4 kblks (1KB); slot s: k=s>>4, rho=((s&15)-4k)&15
// frag read offset(row r, kblk k) = (r>>4)*1024 + k*256 + (((r&15)+4k)&15)*16  -> 0 bank conflicts
__global__ __launch_bounds__(256, 2) void gemm_kernel(
    const int8_t* __restrict__ xq, const int8_t* __restrict__ wq,
    const float* __restrict__ bias, const float* __restrict__ wssc,
    float* __restrict__ out) {

    __shared__ __align__(16) int8_t As0[128 * 64];
    __shared__ __align__(16) int8_t As1[128 * 64];
    __shared__ __align__(16) int8_t Bs0[256 * 64];
    __shared__ __align__(16) int8_t Bs1[256 * 64];

    const int t = threadIdx.x;
    const int lane = t & 63;
    const int wv = t >> 6;
    const int half = lane >> 5;
    const int lr = lane & 31;
    const int wm0 = (wv >> 1) * 64;    // wave m offset within block
    const int wn0 = (wv & 1) * 128;    // wave n offset within block
    const int m0 = blockIdx.x * 128;
    const int n0 = blockIdx.y * 256;

    // ---- staging source pointers: A 2 slots/thread, B 4 slots/thread ----
    const GLOBAL_AS int8_t* aSrc[2];
    const GLOBAL_AS int8_t* bSrc[4];
    int aLds[2], bLds[4];
#pragma unroll
    for (int j = 0; j < 2; ++j) {
        int idx = j * 256 + t;       // 0..511
        int c = idx >> 6;
        int s = idx & 63;
        int k = s >> 4;
        int rho = ((s & 15) - 4 * k) & 15;
        int row = c * 16 + rho;
        aSrc[j] = (const GLOBAL_AS int8_t*)(xq + (size_t)(m0 + row) * K + k * 16);
        aLds[j] = idx * 16;
    }
#pragma unroll
    for (int j = 0; j < 4; ++j) {
        int idx = j * 256 + t;       // 0..1023
        int c = idx >> 6;
        int s = idx & 63;
        int k = s >> 4;
        int rho = ((s & 15) - 4 * k) & 15;
        int row = c * 16 + rho;
        bSrc[j] = (const GLOBAL_AS int8_t*)(wq + (size_t)(n0 + row) * K + k * 16);
        bLds[j] = idx * 16;
    }

    // ---- fragment LDS offsets ----
    int aOff[2][2], bOff[2][4];
#pragma unroll
    for (int ks = 0; ks < 2; ++ks) {
        int k = ks * 2 + half;
#pragma unroll
        for (int q = 0; q < 2; ++q) {
            int r = wm0 + q * 32 + lr;
            aOff[ks][q] = (r >> 4) * 1024 + k * 256 + (((r & 15) + 4 * k) & 15) * 16;
        }
#pragma unroll
        for (int q = 0; q < 4; ++q) {
            int r = wn0 + q * 32 + lr;
            bOff[ks][q] = (r >> 4) * 1024 + k * 256 + (((r & 15) + 4 * k) & 15) * 16;
        }
    }

    v16i acc[2][4];
#pragma unroll
    for (int mt = 0; mt < 2; ++mt)
#pragma unroll
        for (int nt = 0; nt < 4; ++nt)
#pragma unroll
            for (int e = 0; e < 16; ++e) acc[mt][nt][e] = 0;

    auto stage = [&](int kt, int8_t* A, int8_t* B) {
#pragma unroll
        for (int j = 0; j < 2; ++j)
            __builtin_amdgcn_global_load_lds((const GLOBAL_AS void*)(aSrc[j] + kt),
                                             (LDS_AS void*)(A + aLds[j]), 16, 0, 0);
#pragma unroll
        for (int j = 0; j < 4; ++j)
            __builtin_amdgcn_global_load_lds((const GLOBAL_AS void*)(bSrc[j] + kt),
                                             (LDS_AS void*)(B + bLds[j]), 16, 0, 0);
    };

    auto compute = [&](const int8_t* A, const int8_t* B) {
#pragma unroll
        for (int ks = 0; ks < 2; ++ks) {
            v4i a[2], b[4];
#pragma unroll
            for (int q = 0; q < 2; ++q) a[q] = *(const v4i*)(A + aOff[ks][q]);
#pragma unroll
            for (int q = 0; q < 4; ++q) b[q] = *(const v4i*)(B + bOff[ks][q]);
#pragma unroll
            for (int mt = 0; mt < 2; ++mt)
#pragma unroll
                for (int nt = 0; nt < 4; ++nt)
                    acc[mt][nt] = __builtin_amdgcn_mfma_i32_32x32x32_i8(a[mt], b[nt], acc[mt][nt], 0, 0, 0);
        }
    };

    constexpr int NIT = K / 64;  // 64 tiles
    stage(0, As0, Bs0);
    __syncthreads();
#pragma unroll 1
    for (int it = 0; it < NIT - 2; it += 2) {
        stage((it + 1) * 64, As1, Bs1);
        compute(As0, Bs0);
        __syncthreads();
        stage((it + 2) * 64, As0, Bs0);
        compute(As1, Bs1);
        __syncthreads();
    }
    stage((NIT - 1) * 64, As1, Bs1);
    compute(As0, Bs0);
    __syncthreads();
    compute(As1, Bs1);

    // ---- epilogue: C/D layout col=lane&31, row=(reg&3)+8*(reg>>2)+4*(lane>>5) ----
    const float scale = wssc[2];
#pragma unroll
    for (int nt = 0; nt < 4; ++nt) {
        int col = n0 + wn0 + nt * 32 + lr;
        float bv = bias[col];
#pragma unroll
        for (int mt = 0; mt < 2; ++mt) {
            int rb = m0 + wm0 + mt * 32 + 4 * half;
#pragma unroll
            for (int reg = 0; reg < 16; ++reg) {
                int row = rb + (reg & 3) + 8 * (reg >> 2);
                out[(size_t)row * N + col] = (float)acc[mt][nt][reg] * scale + bv;
            }
        }
    }
}

extern "C" void kernel_launch(void* const* d_in, const int* in_sizes, int n_in,
                              void* d_out, int out_size, void* d_ws, size_t ws_size,
                              hipStream_t stream) {
    const float* x = (const float*)d_in[0];     // [8192][4096]
    const float* w = (const float*)d_in[1];     // [4096][4096]
    const float* bias = (const float*)d_in[2];  // [4096]
    float* out = (float*)d_out;                 // [8192][4096]

    float* wssc = (float*)d_ws;
    float* pmax = (float*)((char*)d_ws + 256);          // 2048 f32 -> ends 8448
    double* psum = (double*)((char*)d_ws + 8448);       // 1024 f64 -> ends 16640
    int8_t* xq = (int8_t*)d_ws + 16640;
    int8_t* wq = xq + (size_t)M * K;

    hipLaunchKernelGGL(reduce_kernel, dim3(3072), dim3(256), 0, stream,
                       (const float4*)x, (const float4*)w, pmax, psum);
    hipLaunchKernelGGL(finalize_kernel, dim3(1), dim3(256), 0, stream, wssc, pmax, psum);
    hipLaunchKernelGGL(quant_kernel, dim3(3072), dim3(256), 0, stream,
                       (const float4*)x, (const float4*)w, (int*)xq, (int*)wq, wssc);
    hipLaunchKernelGGL(gemm_kernel, dim3(M / 128, N / 256), dim3(256), 0, stream,
                       xq, wq, bias, wssc, out);
}